// Round 1
// baseline (254.193 us; speedup 1.0000x reference)
//
#include <hip/hip_runtime.h>
#include <cstdint>
#include <cstddef>

// MultiHeadAttention: B=4, S=2048, D=768, H=16, Dh=48, fp32 I/O.
// bf16 MFMA: cvt_all -> fused QKV GEMM -> flash-attn v8 (32x32 MFMA) -> out GEMM
// v8 (this round): double-buffered K/V LDS staging (prefetch tile t+1 while
// computing tile t; ONE barrier per iter, vmcnt drain hidden under ~1000cy of
// compute) + s_setprio(1) around MFMA clusters (T5, proven +4-7% on attn).
// Carried from v7: 32x32x16 MFMA; P C-layout -> A-layout via 2x shfl_xor(32);
// QK skips dh 48..63 pad; K/V DMA = 12 chunks = 3/wave; all LDS frag reads
// xor-swizzled to uniform 8 lanes/bank-quad (b128 floor).

typedef short s8v __attribute__((ext_vector_type(8)));    // 8 x bf16 (4 VGPRs)
typedef float f4v __attribute__((ext_vector_type(4)));    // 16x16 accumulator
typedef float f16v __attribute__((ext_vector_type(16)));  // 32x32 accumulator

static constexpr int Bn = 4, Sn = 2048, Dn = 768, Hn = 16, DhN = 48, Dp = 64;
static constexpr int MS = Bn * Sn;  // 8192 rows

#define MFMA16(a, b, c) __builtin_amdgcn_mfma_f32_16x16x32_bf16((a), (b), (c), 0, 0, 0)
#define MFMA32(a, b, c) __builtin_amdgcn_mfma_f32_32x32x16_bf16((a), (b), (c), 0, 0, 0)

__device__ __forceinline__ int swz4(int r) { return (r + (r >> 2)) & 3; }

__device__ __forceinline__ ushort f2b(float f) {
  return (ushort)((__builtin_bit_cast(uint32_t, f) + 0x8000u) >> 16);
}
// pack hi16(a+0x8000), hi16(b+0x8000) via v_perm_b32 (a -> low half)
__device__ __forceinline__ uint32_t packbf(float a, float b) {
  uint32_t ua = __builtin_bit_cast(uint32_t, a) + 0x8000u;
  uint32_t ub = __builtin_bit_cast(uint32_t, b) + 0x8000u;
  return __builtin_amdgcn_perm(ub, ua, 0x07060302u);
}
__device__ __forceinline__ float fexp2(float x) {
  return __builtin_amdgcn_exp2f(x);
}
__device__ __forceinline__ void gload_lds16(const ushort* g, ushort* l) {
  __builtin_amdgcn_global_load_lds(
      (const __attribute__((address_space(1))) uint32_t*)g,
      (__attribute__((address_space(3))) uint32_t*)l, 16, 0, 0);
}

// One launch converts x (6144 blocks) + 4 weights (4*576 blocks) to bf16.
__global__ void cvt_all(const float* __restrict__ x,
                        const float* __restrict__ wq, const float* __restrict__ wk,
                        const float* __restrict__ wv, const float* __restrict__ wo,
                        ushort* __restrict__ xb, ushort* __restrict__ wqkv,
                        ushort* __restrict__ wob) {
  const int bid = blockIdx.x;
  const float* src;
  ushort* dst;
  int i;
  if (bid < 6144) {
    src = x; dst = xb; i = bid * 256 + threadIdx.x;
  } else {
    const int r = (bid - 6144) / 576;
    i = ((bid - 6144) % 576) * 256 + threadIdx.x;
    src = (r == 0) ? wq : (r == 1) ? wk : (r == 2) ? wv : wo;
    dst = (r < 3) ? (wqkv + (size_t)r * Dn * Dn) : wob;
  }
  float4 f = ((const float4*)src)[i];
  ushort4 o = { f2b(f.x), f2b(f.y), f2b(f.z), f2b(f.w) };
  ((ushort4*)dst)[i] = o;
}

// ---- Fused QKV GEMM (A=W, B=x so acc regs = 4 consecutive n). Swizzled LDS.
// region 0 -> q [B,H,S,64] (*qscale), 1 -> k [B,H,S,64], 2 -> v [B,H,48,S]
// (q/k Dh-pad cols 48..63 are never read by attn -> no pad zeroing needed)
__global__ __launch_bounds__(256) void gemm_qkv(
    const ushort* __restrict__ A, const ushort* __restrict__ W,
    const float* __restrict__ bq, const float* __restrict__ bk, const float* __restrict__ bv,
    ushort* __restrict__ outq, ushort* __restrict__ outk, ushort* __restrict__ outv,
    float qscale) {
  __shared__ __align__(16) ushort As[128][32];   // x rows
  __shared__ __align__(16) ushort Bs[128][32];   // W rows
  const int tid = threadIdx.x, lane = tid & 63, wave = tid >> 6;
  const int l15 = lane & 15, g = lane >> 4;
  const int m0 = blockIdx.y * 128, n0 = blockIdx.x * 128;
  const int wqm = (wave >> 1) * 64;   // weight-dim quadrant
  const int wqx = (wave & 1) * 64;    // x-dim quadrant
  f4v acc[4][4] = {};                 // [i=wtile][j=xtile]

  const int slot0 = wave * 128 + lane;
  const int slot1 = slot0 + 64;
  const int r0 = slot0 >> 2, u0 = ((slot0 & 3) ^ swz4(r0 & 15)) * 8;
  const int r1 = slot1 >> 2, u1 = ((slot1 & 3) ^ swz4(r1 & 15)) * 8;
  const ushort* ag0 = A + (size_t)(m0 + r0) * Dn + u0;
  const ushort* ag1 = A + (size_t)(m0 + r1) * Dn + u1;
  const ushort* bg0 = W + (size_t)(n0 + r0) * Dn + u0;
  const ushort* bg1 = W + (size_t)(n0 + r1) * Dn + u1;
  ushort* lA0 = &As[0][0] + slot0 * 8;
  ushort* lA1 = &As[0][0] + slot1 * 8;
  ushort* lB0 = &Bs[0][0] + slot0 * 8;
  ushort* lB1 = &Bs[0][0] + slot1 * 8;
  const int fcol = (g ^ swz4(l15)) * 8;

  for (int k0 = 0; k0 < Dn; k0 += 32) {
    __syncthreads();
    gload_lds16(ag0 + k0, lA0);
    gload_lds16(ag1 + k0, lA1);
    gload_lds16(bg0 + k0, lB0);
    gload_lds16(bg1 + k0, lB1);
    __syncthreads();
    s8v wf[4], xf[4];
#pragma unroll
    for (int i = 0; i < 4; ++i) wf[i] = *(const s8v*)&Bs[wqm + i * 16 + l15][fcol];
#pragma unroll
    for (int j = 0; j < 4; ++j) xf[j] = *(const s8v*)&As[wqx + j * 16 + l15][fcol];
#pragma unroll
    for (int i = 0; i < 4; ++i)
#pragma unroll
      for (int j = 0; j < 4; ++j) acc[i][j] = MFMA16(wf[i], xf[j], acc[i][j]);
  }

  const int region = blockIdx.x / 6;        // uniform per block
  const int nbase = n0 - region * 768;
  const float* bias = (region == 0) ? bq : (region == 1) ? bk : bv;
#pragma unroll
  for (int i = 0; i < 4; ++i) {
    const int n = nbase + wqm + i * 16 + g * 4;   // 4 consecutive n, same head
    const float4 b4 = *(const float4*)&bias[n];
    const int h = n / DhN, dh = n - h * DhN;
#pragma unroll
    for (int j = 0; j < 4; ++j) {
      const int s = m0 + wqx + j * 16 + l15;
      const int b = s >> 11, srow = s & 2047;
      const int bh = b * Hn + h;
      float v0 = acc[i][j][0] + b4.x, v1 = acc[i][j][1] + b4.y;
      float v2 = acc[i][j][2] + b4.z, v3 = acc[i][j][3] + b4.w;
      if (region == 0) { v0 *= qscale; v1 *= qscale; v2 *= qscale; v3 *= qscale; }
      if (region < 2) {
        ushort4 o = { f2b(v0), f2b(v1), f2b(v2), f2b(v3) };
        ushort* dst = region ? outk : outq;
        *(ushort4*)&dst[((size_t)bh * Sn + srow) * Dp + dh] = o;
      } else {
        outv[((size_t)bh * DhN + dh + 0) * Sn + srow] = f2b(v0);
        outv[((size_t)bh * DhN + dh + 1) * Sn + srow] = f2b(v1);
        outv[((size_t)bh * DhN + dh + 2) * Sn + srow] = f2b(v2);
        outv[((size_t)bh * DhN + dh + 3) * Sn + srow] = f2b(v3);
      }
    }
  }
}

// ---- Out projection GEMM (swapped operands, float4 stores). Swizzled LDS.
__global__ __launch_bounds__(256) void gemm_out(
    const ushort* __restrict__ A, const ushort* __restrict__ W,
    const float* __restrict__ bias, float* __restrict__ out) {
  __shared__ __align__(16) ushort As[128][32];
  __shared__ __align__(16) ushort Bs[128][32];
  const int tid = threadIdx.x, lane = tid & 63, wave = tid >> 6;
  const int l15 = lane & 15, g = lane >> 4;
  const int m0 = blockIdx.y * 128, n0 = blockIdx.x * 128;
  const int wqm = (wave >> 1) * 64;
  const int wqx = (wave & 1) * 64;
  f4v acc[4][4] = {};

  const int slot0 = wave * 128 + lane;
  const int slot1 = slot0 + 64;
  const int r0 = slot0 >> 2, u0 = ((slot0 & 3) ^ swz4(r0 & 15)) * 8;
  const int r1 = slot1 >> 2, u1 = ((slot1 & 3) ^ swz4(r1 & 15)) * 8;
  const ushort* ag0 = A + (size_t)(m0 + r0) * Dn + u0;
  const ushort* ag1 = A + (size_t)(m0 + r1) * Dn + u1;
  const ushort* bg0 = W + (size_t)(n0 + r0) * Dn + u0;
  const ushort* bg1 = W + (size_t)(n0 + r1) * Dn + u1;
  ushort* lA0 = &As[0][0] + slot0 * 8;
  ushort* lA1 = &As[0][0] + slot1 * 8;
  ushort* lB0 = &Bs[0][0] + slot0 * 8;
  ushort* lB1 = &Bs[0][0] + slot1 * 8;
  const int fcol = (g ^ swz4(l15)) * 8;

  for (int k0 = 0; k0 < Dn; k0 += 32) {
    __syncthreads();
    gload_lds16(ag0 + k0, lA0);
    gload_lds16(ag1 + k0, lA1);
    gload_lds16(bg0 + k0, lB0);
    gload_lds16(bg1 + k0, lB1);
    __syncthreads();
    s8v wf[4], xf[4];
#pragma unroll
    for (int i = 0; i < 4; ++i) wf[i] = *(const s8v*)&Bs[wqm + i * 16 + l15][fcol];
#pragma unroll
    for (int j = 0; j < 4; ++j) xf[j] = *(const s8v*)&As[wqx + j * 16 + l15][fcol];
#pragma unroll
    for (int i = 0; i < 4; ++i)
#pragma unroll
      for (int j = 0; j < 4; ++j) acc[i][j] = MFMA16(wf[i], xf[j], acc[i][j]);
  }

#pragma unroll
  for (int i = 0; i < 4; ++i) {
    const int n = n0 + wqm + i * 16 + g * 4;
    const float4 b4 = *(const float4*)&bias[n];
#pragma unroll
    for (int j = 0; j < 4; ++j) {
      const int s = m0 + wqx + j * 16 + l15;
      float4 o4 = { acc[i][j][0] + b4.x, acc[i][j][1] + b4.y,
                    acc[i][j][2] + b4.z, acc[i][j][3] + b4.w };
      *(float4*)&out[(size_t)s * Dn + n] = o4;
    }
  }
}

// ---- Flash attention v8. grid = (S/128 = 16, B*H), block 256 (4 waves x 32 q).
// 32x32x16 MFMA. Per 64-key iter per wave: QK = 2x3 MFMA (dh 0..47 only),
// P transform in registers (shfl_xor 32), PV = 2x2x2 MFMA (ones-row -> lsum).
// DOUBLE-BUFFERED LDS 28KB: {Ka[64][32], Kb[64][16], Vs[64][64]} x2.
// Loop: issue DMA(tile t+1 -> buf^1); compute(buf); ONE __syncthreads (its
// vmcnt drain lands after ~1000cy of compute -> latency hidden).
__global__ __launch_bounds__(256) void attn_kernel(
    const ushort* __restrict__ qg, const ushort* __restrict__ kg,
    const ushort* __restrict__ vg, ushort* __restrict__ og) {
  __shared__ __align__(16) ushort Ka[2][64][32];
  __shared__ __align__(16) ushort Kb[2][64][16];
  __shared__ __align__(16) ushort Vs[2][64][64];
  const int tid = threadIdx.x;
  const int lane = tid & 63;
  const int wave = tid >> 6;          // 0..3
  const int l31 = lane & 31;
  const int h = lane >> 5;            // 0..1
  const int bh = blockIdx.y;
  const int q0 = blockIdx.x * 128;
  const ushort* qb = qg + (size_t)bh * Sn * Dp;
  const ushort* kb = kg + (size_t)bh * Sn * Dp;
  const ushort* vb = vg + (size_t)bh * DhN * Sn;

  // static V rows 48..63 (both buffers): row 48 = 1.0 (lsum via MFMA), rest 0
#pragma unroll
  for (int d = 0; d < 2; ++d)
#pragma unroll
    for (int t = 0; t < 2; ++t) {
      const int idx = tid + t * 256;            // 0..511 dwords over rows 48..63
      const int row = 48 + (idx >> 5);
      ((uint32_t*)&Vs[d][row][0])[idx & 31] = (row == 48) ? 0x3F803F80u : 0u;
    }

  // Q B-frags (n=q=lane&31, k=dh): kc 0..2 covers dh 0..47 (pad skipped)
  s8v qf[3];
#pragma unroll
  for (int kc = 0; kc < 3; ++kc)
    qf[kc] = *(const s8v*)(qb + (size_t)(q0 + wave * 32 + l31) * Dp + kc * 16 + h * 8);

  // DMA: 12 x 1KB chunks, wave w takes c = w + 4t (t=0..2) -> exactly 3 each.
  // Source col xor-swizzled so frag reads hit uniform 8 lanes/bank-quad.
  const ushort* gsrc[3];
  ushort* ldst0[3];   // chunk dest in buffer 0
  ushort* ldst1[3];   // chunk dest in buffer 1
  int gstep[3];
#pragma unroll
  for (int t = 0; t < 3; ++t) {
    const int c = wave + 4 * t;
    if (c < 4) {            // Ka: rows 16c..16c+15, dh 0..31 (16 rows x 4 slots)
      const int row = 16 * c + (lane >> 2), j = lane & 3;
      gsrc[t] = kb + (size_t)row * Dp + (j ^ ((row >> 1) & 3)) * 8;
      ldst0[t] = &Ka[0][0][0] + 16 * c * 32 + lane * 8;
      ldst1[t] = ldst0[t] + 64 * 32;
      gstep[t] = 64 * Dp;
    } else if (c < 6) {     // Kb: rows 32(c-4)..+31, dh 32..47 (32 rows x 2 slots)
      const int row = 32 * (c - 4) + (lane >> 1), j = lane & 1;
      gsrc[t] = kb + (size_t)row * Dp + 32 + (j ^ ((row >> 2) & 1)) * 8;
      ldst0[t] = &Kb[0][0][0] + 32 * (c - 4) * 16 + lane * 8;
      ldst1[t] = ldst0[t] + 64 * 16;
      gstep[t] = 64 * Dp;
    } else {                // V: rows 8(c-6)..+7 (8 rows x 8 slots)
      const int row = 8 * (c - 6) + (lane >> 3), j = lane & 7;
      gsrc[t] = vb + (size_t)row * Sn + (j ^ (row & 7)) * 8;
      ldst0[t] = &Vs[0][0][0] + 8 * (c - 6) * 64 + lane * 8;
      ldst1[t] = ldst0[t] + 64 * 64;
      gstep[t] = 64;
    }
  }

  f16v o0 = {}, o1 = {};   // O cols dh 0..31 / dh 32..63 (col 16 of o1 = lsum)

  // prologue: stage tile 0 into buffer 0
#pragma unroll
  for (int t = 0; t < 3; ++t) {
    gload_lds16(gsrc[t], ldst0[t]);
    gsrc[t] += gstep[t];
  }
  __syncthreads();

  int cur = 0;
  for (int kt = 0; kt < Sn; kt += 64) {
    // issue next tile's DMA into the other buffer (in flight during compute)
    if (kt < Sn - 64) {
#pragma unroll
      for (int t = 0; t < 3; ++t) {
        gload_lds16(gsrc[t], cur ? ldst0[t] : ldst1[t]);
        gsrc[t] += gstep[t];
      }
    }
    const ushort(*KaC)[32] = Ka[cur];
    const ushort(*KbC)[16] = Kb[cur];
    const ushort(*VsC)[64] = Vs[cur];

#pragma unroll
    for (int mg = 0; mg < 2; ++mg) {        // key group: 32 keys
      const int row = 32 * mg + l31;        // key for A-frag
      const int s1 = (l31 >> 1) & 3, s2 = (l31 >> 2) & 1;
      s8v a0 = *(const s8v*)&KaC[row][((0 | h) ^ s1) * 8];
      s8v a1 = *(const s8v*)&KaC[row][((2 | h) ^ s1) * 8];
      s8v a2 = *(const s8v*)&KbC[row][((h) ^ s2) * 8];
      f16v sc = {};
      __builtin_amdgcn_s_setprio(1);
      sc = MFMA32(a0, qf[0], sc);
      sc = MFMA32(a1, qf[1], sc);
      sc = MFMA32(a2, qf[2], sc);           // S^T: col=q(lane&31), row=key(reg,h)
      __builtin_amdgcn_s_setprio(0);
      float p[16];
#pragma unroll
      for (int r = 0; r < 16; ++r) p[r] = fexp2(sc[r]);

#pragma unroll
      for (int c2 = 0; c2 < 2; ++c2) {      // 16-key chunks of this group
        const int rb = 8 * c2;
        const uint32_t lo0 = packbf(p[rb + 0], p[rb + 1]);
        const uint32_t lo1 = packbf(p[rb + 2], p[rb + 3]);
        const uint32_t hi0 = packbf(p[rb + 4], p[rb + 5]);
        const uint32_t hi1 = packbf(p[rb + 6], p[rb + 7]);
        // C-layout -> A-layout: lanes L and L^32 swap half their regs
        const uint32_t t0 = __shfl_xor(h ? lo0 : hi0, 32, 64);
        const uint32_t t1 = __shfl_xor(h ? lo1 : hi1, 32, 64);
        uint4 af;
        af.x = h ? t0 : lo0;
        af.y = h ? t1 : lo1;
        af.z = h ? hi0 : t0;
        af.w = h ? hi1 : t1;
        const s8v pa = __builtin_bit_cast(s8v, af);
        const int kcv = 2 * mg + c2;        // 16-key chunk index in the 64-key tile
        const int vc = ((2 * kcv + h) ^ (l31 & 7)) * 8;
        const s8v v0 = *(const s8v*)&VsC[l31][vc];
        const s8v v1 = *(const s8v*)&VsC[32 + l31][vc];
        __builtin_amdgcn_s_setprio(1);
        o0 = MFMA32(pa, v0, o0);
        o1 = MFMA32(pa, v1, o1);
        __builtin_amdgcn_s_setprio(0);
      }
    }
    __syncthreads();
    cur ^= 1;
  }

  const int b = bh >> 4, hh = bh & 15;
#pragma unroll
  for (int r = 0; r < 16; ++r) {
    const int q = (r & 3) + 8 * (r >> 2) + 4 * h;
    const float lsum = __shfl(o1[r], 16 + (lane & 32), 64);  // col 16 = dh48 = ones row
    const float inv = 1.0f / lsum;
    const int s = q0 + wave * 32 + q;
    const size_t base = ((size_t)(b * Sn + s)) * Dn + hh * DhN;
    og[base + l31] = f2b(o0[r] * inv);
    if (l31 < 16) og[base + 32 + l31] = f2b(o1[r] * inv);
  }
}

extern "C" void kernel_launch(void* const* d_in, const int* in_sizes, int n_in,
                              void* d_out, int out_size, void* d_ws, size_t ws_size,
                              hipStream_t stream) {
  (void)in_sizes; (void)n_in; (void)out_size; (void)ws_size;
  const float* x  = (const float*)d_in[0];
  const float* Wq = (const float*)d_in[1];
  const float* bq = (const float*)d_in[2];
  const float* Wk = (const float*)d_in[3];
  const float* bk = (const float*)d_in[4];
  const float* Wv = (const float*)d_in[5];
  const float* bv = (const float*)d_in[6];
  const float* Wo = (const float*)d_in[7];
  const float* bo = (const float*)d_in[8];

  size_t off = 0;
  auto alloc = [&](size_t bytes) {
    void* p = (char*)d_ws + off;
    off += (bytes + 255) & ~(size_t)255;
    return p;
  };
  ushort* xb    = (ushort*)alloc((size_t)MS * Dn * 2);
  ushort* Wqkvb = (ushort*)alloc((size_t)3 * Dn * Dn * 2);
  ushort* Wob   = (ushort*)alloc((size_t)Dn * Dn * 2);
  ushort* qbuf  = (ushort*)alloc((size_t)Bn * Hn * Sn * Dp * 2);
  ushort* kbuf  = (ushort*)alloc((size_t)Bn * Hn * Sn * Dp * 2);
  ushort* vbuf  = (ushort*)alloc((size_t)Bn * Hn * DhN * Sn * 2);
  ushort* ao    = (ushort*)alloc((size_t)MS * Dn * 2);

  cvt_all<<<6144 + 4 * 576, 256, 0, stream>>>(x, Wq, Wk, Wv, Wo, xb, Wqkvb, Wob);

  const dim3 blk(256);
  // scale = log2(e)/sqrt(48): softmax computed in exp2 domain
  const float qscale = 0.20823510929813633f;
  gemm_qkv<<<dim3(18, MS / 128), blk, 0, stream>>>(xb, Wqkvb, bq, bk, bv,
                                                   qbuf, kbuf, vbuf, qscale);

  attn_kernel<<<dim3(Sn / 128, Bn * Hn), blk, 0, stream>>>(qbuf, kbuf, vbuf, ao);

  gemm_out<<<dim3(6, MS / 128), blk, 0, stream>>>(ao, Wob, bo, (float*)d_out);
}

// Round 3
// 244.847 us; speedup vs baseline: 1.0382x; 1.0382x over previous
//
#include <hip/hip_runtime.h>
#include <cstdint>
#include <cstddef>

// MultiHeadAttention: B=4, S=2048, D=768, H=16, Dh=48, fp32 I/O.
// bf16 MFMA: cvt_all -> fused QKV GEMM -> flash-attn v10 (32x32 MFMA) -> out GEMM
// v10: v9's cvt_pk_bf16_f32 caused a rounding-mode absmax fail (7.7e-3) ->
// revert pack to baseline's packbf (+0x8000 truncate, bit-exact with the
// passing 252us version). KEEP: (a) permlane32_swap for the P half-exchange
// (2 VALU ops replace 2 ds_bpermute + 6 cndmask per 16-key chunk; equivalence
// re-derived: swap(lo,hi) -> {lo.lo,hi.lo},{lo.hi,hi.hi} = exactly the old
// shfl_xor network), (b) XCD-aware block swizzle (bijective: XCD c owns heads
// [8c,8c+8), 3.6MB K/V fits one 4MB L2 -> FETCH 123MB -> ~50MB).
// Carried from v7: single-buffer LDS, 32x32x16 MFMA, QK skips dh 48..63 pad,
// K/V DMA = 12 chunks = 3/wave, frag reads xor-swizzled (b128 floor).

typedef short s8v __attribute__((ext_vector_type(8)));    // 8 x bf16 (4 VGPRs)
typedef float f4v __attribute__((ext_vector_type(4)));    // 16x16 accumulator
typedef float f16v __attribute__((ext_vector_type(16)));  // 32x32 accumulator

static constexpr int Bn = 4, Sn = 2048, Dn = 768, Hn = 16, DhN = 48, Dp = 64;
static constexpr int MS = Bn * Sn;  // 8192 rows

#define MFMA16(a, b, c) __builtin_amdgcn_mfma_f32_16x16x32_bf16((a), (b), (c), 0, 0, 0)
#define MFMA32(a, b, c) __builtin_amdgcn_mfma_f32_32x32x16_bf16((a), (b), (c), 0, 0, 0)

__device__ __forceinline__ int swz4(int r) { return (r + (r >> 2)) & 3; }

__device__ __forceinline__ ushort f2b(float f) {
  return (ushort)((__builtin_bit_cast(uint32_t, f) + 0x8000u) >> 16);
}
// pack hi16(a+0x8000), hi16(b+0x8000) via v_perm_b32 (a -> low half)
__device__ __forceinline__ uint32_t packbf(float a, float b) {
  uint32_t ua = __builtin_bit_cast(uint32_t, a) + 0x8000u;
  uint32_t ub = __builtin_bit_cast(uint32_t, b) + 0x8000u;
  return __builtin_amdgcn_perm(ub, ua, 0x07060302u);
}
// swap upper 32 lanes of a with lower 32 lanes of b (in place, both usable)
__device__ __forceinline__ void pl32swap(uint32_t& a, uint32_t& b) {
  asm("v_permlane32_swap_b32 %0, %1" : "+v"(a), "+v"(b));
}
__device__ __forceinline__ float fexp2(float x) {
  return __builtin_amdgcn_exp2f(x);
}
__device__ __forceinline__ void gload_lds16(const ushort* g, ushort* l) {
  __builtin_amdgcn_global_load_lds(
      (const __attribute__((address_space(1))) uint32_t*)g,
      (__attribute__((address_space(3))) uint32_t*)l, 16, 0, 0);
}

// One launch converts x (6144 blocks) + 4 weights (4*576 blocks) to bf16.
__global__ void cvt_all(const float* __restrict__ x,
                        const float* __restrict__ wq, const float* __restrict__ wk,
                        const float* __restrict__ wv, const float* __restrict__ wo,
                        ushort* __restrict__ xb, ushort* __restrict__ wqkv,
                        ushort* __restrict__ wob) {
  const int bid = blockIdx.x;
  const float* src;
  ushort* dst;
  int i;
  if (bid < 6144) {
    src = x; dst = xb; i = bid * 256 + threadIdx.x;
  } else {
    const int r = (bid - 6144) / 576;
    i = ((bid - 6144) % 576) * 256 + threadIdx.x;
    src = (r == 0) ? wq : (r == 1) ? wk : (r == 2) ? wv : wo;
    dst = (r < 3) ? (wqkv + (size_t)r * Dn * Dn) : wob;
  }
  float4 f = ((const float4*)src)[i];
  ushort4 o = { f2b(f.x), f2b(f.y), f2b(f.z), f2b(f.w) };
  ((ushort4*)dst)[i] = o;
}

// ---- Fused QKV GEMM (A=W, B=x so acc regs = 4 consecutive n). Swizzled LDS.
// region 0 -> q [B,H,S,64] (*qscale), 1 -> k [B,H,S,64], 2 -> v [B,H,48,S]
// (q/k Dh-pad cols 48..63 are never read by attn -> no pad zeroing needed)
__global__ __launch_bounds__(256) void gemm_qkv(
    const ushort* __restrict__ A, const ushort* __restrict__ W,
    const float* __restrict__ bq, const float* __restrict__ bk, const float* __restrict__ bv,
    ushort* __restrict__ outq, ushort* __restrict__ outk, ushort* __restrict__ outv,
    float qscale) {
  __shared__ __align__(16) ushort As[128][32];   // x rows
  __shared__ __align__(16) ushort Bs[128][32];   // W rows
  const int tid = threadIdx.x, lane = tid & 63, wave = tid >> 6;
  const int l15 = lane & 15, g = lane >> 4;
  const int m0 = blockIdx.y * 128, n0 = blockIdx.x * 128;
  const int wqm = (wave >> 1) * 64;   // weight-dim quadrant
  const int wqx = (wave & 1) * 64;    // x-dim quadrant
  f4v acc[4][4] = {};                 // [i=wtile][j=xtile]

  const int slot0 = wave * 128 + lane;
  const int slot1 = slot0 + 64;
  const int r0 = slot0 >> 2, u0 = ((slot0 & 3) ^ swz4(r0 & 15)) * 8;
  const int r1 = slot1 >> 2, u1 = ((slot1 & 3) ^ swz4(r1 & 15)) * 8;
  const ushort* ag0 = A + (size_t)(m0 + r0) * Dn + u0;
  const ushort* ag1 = A + (size_t)(m0 + r1) * Dn + u1;
  const ushort* bg0 = W + (size_t)(n0 + r0) * Dn + u0;
  const ushort* bg1 = W + (size_t)(n0 + r1) * Dn + u1;
  ushort* lA0 = &As[0][0] + slot0 * 8;
  ushort* lA1 = &As[0][0] + slot1 * 8;
  ushort* lB0 = &Bs[0][0] + slot0 * 8;
  ushort* lB1 = &Bs[0][0] + slot1 * 8;
  const int fcol = (g ^ swz4(l15)) * 8;

  for (int k0 = 0; k0 < Dn; k0 += 32) {
    __syncthreads();
    gload_lds16(ag0 + k0, lA0);
    gload_lds16(ag1 + k0, lA1);
    gload_lds16(bg0 + k0, lB0);
    gload_lds16(bg1 + k0, lB1);
    __syncthreads();
    s8v wf[4], xf[4];
#pragma unroll
    for (int i = 0; i < 4; ++i) wf[i] = *(const s8v*)&Bs[wqm + i * 16 + l15][fcol];
#pragma unroll
    for (int j = 0; j < 4; ++j) xf[j] = *(const s8v*)&As[wqx + j * 16 + l15][fcol];
#pragma unroll
    for (int i = 0; i < 4; ++i)
#pragma unroll
      for (int j = 0; j < 4; ++j) acc[i][j] = MFMA16(wf[i], xf[j], acc[i][j]);
  }

  const int region = blockIdx.x / 6;        // uniform per block
  const int nbase = n0 - region * 768;
  const float* bias = (region == 0) ? bq : (region == 1) ? bk : bv;
#pragma unroll
  for (int i = 0; i < 4; ++i) {
    const int n = nbase + wqm + i * 16 + g * 4;   // 4 consecutive n, same head
    const float4 b4 = *(const float4*)&bias[n];
    const int h = n / DhN, dh = n - h * DhN;
#pragma unroll
    for (int j = 0; j < 4; ++j) {
      const int s = m0 + wqx + j * 16 + l15;
      const int b = s >> 11, srow = s & 2047;
      const int bh = b * Hn + h;
      float v0 = acc[i][j][0] + b4.x, v1 = acc[i][j][1] + b4.y;
      float v2 = acc[i][j][2] + b4.z, v3 = acc[i][j][3] + b4.w;
      if (region == 0) { v0 *= qscale; v1 *= qscale; v2 *= qscale; v3 *= qscale; }
      if (region < 2) {
        ushort4 o = { f2b(v0), f2b(v1), f2b(v2), f2b(v3) };
        ushort* dst = region ? outk : outq;
        *(ushort4*)&dst[((size_t)bh * Sn + srow) * Dp + dh] = o;
      } else {
        outv[((size_t)bh * DhN + dh + 0) * Sn + srow] = f2b(v0);
        outv[((size_t)bh * DhN + dh + 1) * Sn + srow] = f2b(v1);
        outv[((size_t)bh * DhN + dh + 2) * Sn + srow] = f2b(v2);
        outv[((size_t)bh * DhN + dh + 3) * Sn + srow] = f2b(v3);
      }
    }
  }
}

// ---- Out projection GEMM (swapped operands, float4 stores). Swizzled LDS.
__global__ __launch_bounds__(256) void gemm_out(
    const ushort* __restrict__ A, const ushort* __restrict__ W,
    const float* __restrict__ bias, float* __restrict__ out) {
  __shared__ __align__(16) ushort As[128][32];
  __shared__ __align__(16) ushort Bs[128][32];
  const int tid = threadIdx.x, lane = tid & 63, wave = tid >> 6;
  const int l15 = lane & 15, g = lane >> 4;
  const int m0 = blockIdx.y * 128, n0 = blockIdx.x * 128;
  const int wqm = (wave >> 1) * 64;
  const int wqx = (wave & 1) * 64;
  f4v acc[4][4] = {};

  const int slot0 = wave * 128 + lane;
  const int slot1 = slot0 + 64;
  const int r0 = slot0 >> 2, u0 = ((slot0 & 3) ^ swz4(r0 & 15)) * 8;
  const int r1 = slot1 >> 2, u1 = ((slot1 & 3) ^ swz4(r1 & 15)) * 8;
  const ushort* ag0 = A + (size_t)(m0 + r0) * Dn + u0;
  const ushort* ag1 = A + (size_t)(m0 + r1) * Dn + u1;
  const ushort* bg0 = W + (size_t)(n0 + r0) * Dn + u0;
  const ushort* bg1 = W + (size_t)(n0 + r1) * Dn + u1;
  ushort* lA0 = &As[0][0] + slot0 * 8;
  ushort* lA1 = &As[0][0] + slot1 * 8;
  ushort* lB0 = &Bs[0][0] + slot0 * 8;
  ushort* lB1 = &Bs[0][0] + slot1 * 8;
  const int fcol = (g ^ swz4(l15)) * 8;

  for (int k0 = 0; k0 < Dn; k0 += 32) {
    __syncthreads();
    gload_lds16(ag0 + k0, lA0);
    gload_lds16(ag1 + k0, lA1);
    gload_lds16(bg0 + k0, lB0);
    gload_lds16(bg1 + k0, lB1);
    __syncthreads();
    s8v wf[4], xf[4];
#pragma unroll
    for (int i = 0; i < 4; ++i) wf[i] = *(const s8v*)&Bs[wqm + i * 16 + l15][fcol];
#pragma unroll
    for (int j = 0; j < 4; ++j) xf[j] = *(const s8v*)&As[wqx + j * 16 + l15][fcol];
#pragma unroll
    for (int i = 0; i < 4; ++i)
#pragma unroll
      for (int j = 0; j < 4; ++j) acc[i][j] = MFMA16(wf[i], xf[j], acc[i][j]);
  }

#pragma unroll
  for (int i = 0; i < 4; ++i) {
    const int n = n0 + wqm + i * 16 + g * 4;
    const float4 b4 = *(const float4*)&bias[n];
#pragma unroll
    for (int j = 0; j < 4; ++j) {
      const int s = m0 + wqx + j * 16 + l15;
      float4 o4 = { acc[i][j][0] + b4.x, acc[i][j][1] + b4.y,
                    acc[i][j][2] + b4.z, acc[i][j][3] + b4.w };
      *(float4*)&out[(size_t)s * Dn + n] = o4;
    }
  }
}

// ---- Flash attention v10. grid = (16, B*H) remapped so XCD c owns heads
// [8c, 8c+8) (linear block id % 8 == XCD on MI355X round-robin dispatch).
// block 256 (4 waves x 32 q). 32x32x16 MFMA. Per 64-key iter per wave:
// QK = 2x3 MFMA (dh 0..47 only), P transform = packbf x4 (bit-exact with
// baseline) + permlane32_swap x2 per 16-key chunk (in-register, no LDS pipe),
// PV = 2x2x2 MFMA (ones-row -> lsum).
// LDS 14KB: Ka[64][32] dh0..31, Kb[64][16] dh32..47, Vs[64][64] (rows 48..63 static).
__global__ __launch_bounds__(256) void attn_kernel(
    const ushort* __restrict__ qg, const ushort* __restrict__ kg,
    const ushort* __restrict__ vg, ushort* __restrict__ og) {
  __shared__ __align__(16) ushort Ka[64][32];
  __shared__ __align__(16) ushort Kb[64][16];
  __shared__ __align__(16) ushort Vs[64][64];
  const int tid = threadIdx.x;
  const int lane = tid & 63;
  const int wave = tid >> 6;          // 0..3
  const int l31 = lane & 31;
  const int h = lane >> 5;            // 0..1
  // XCD swizzle: lin%8 = XCD c; give XCD c heads [8c,8c+8) x all 16 q-tiles
  // (8 heads x 448KB K/V = 3.6MB fits one 4MB XCD L2). Bijective on [0,1024).
  const int lin = blockIdx.x + (blockIdx.y << 4);
  const int k8 = lin >> 3;
  const int bh = (lin & 7) * 8 + (k8 >> 4);
  const int q0 = (k8 & 15) * 128;
  const ushort* qb = qg + (size_t)bh * Sn * Dp;
  const ushort* kb = kg + (size_t)bh * Sn * Dp;
  const ushort* vb = vg + (size_t)bh * DhN * Sn;

  // static V rows 48..63: row 48 = 1.0 (lsum via MFMA), rest 0
#pragma unroll
  for (int t = 0; t < 2; ++t) {
    const int idx = tid + t * 256;            // 0..511 dwords over rows 48..63
    const int row = 48 + (idx >> 5);
    ((uint32_t*)&Vs[row][0])[idx & 31] = (row == 48) ? 0x3F803F80u : 0u;
  }

  // Q B-frags (n=q=lane&31, k=dh): kc 0..2 covers dh 0..47 (pad skipped)
  s8v qf[3];
#pragma unroll
  for (int kc = 0; kc < 3; ++kc)
    qf[kc] = *(const s8v*)(qb + (size_t)(q0 + wave * 32 + l31) * Dp + kc * 16 + h * 8);

  // DMA: 12 x 1KB chunks, wave w takes c = w + 4t (t=0..2) -> exactly 3 each.
  // Source col xor-swizzled so frag reads hit uniform 8 lanes/bank-quad.
  const ushort* gsrc[3];
  ushort* ldst[3];
  int gstep[3];
#pragma unroll
  for (int t = 0; t < 3; ++t) {
    const int c = wave + 4 * t;
    if (c < 4) {            // Ka: rows 16c..16c+15, dh 0..31 (16 rows x 4 slots)
      const int row = 16 * c + (lane >> 2), j = lane & 3;
      gsrc[t] = kb + (size_t)row * Dp + (j ^ ((row >> 1) & 3)) * 8;
      ldst[t] = &Ka[0][0] + 16 * c * 32 + lane * 8;
      gstep[t] = 64 * Dp;
    } else if (c < 6) {     // Kb: rows 32(c-4)..+31, dh 32..47 (32 rows x 2 slots)
      const int row = 32 * (c - 4) + (lane >> 1), j = lane & 1;
      gsrc[t] = kb + (size_t)row * Dp + 32 + (j ^ ((row >> 2) & 1)) * 8;
      ldst[t] = &Kb[0][0] + 32 * (c - 4) * 16 + lane * 8;
      gstep[t] = 64 * Dp;
    } else {                // V: rows 8(c-6)..+7 (8 rows x 8 slots)
      const int row = 8 * (c - 6) + (lane >> 3), j = lane & 7;
      gsrc[t] = vb + (size_t)row * Sn + (j ^ (row & 7)) * 8;
      ldst[t] = &Vs[0][0] + 8 * (c - 6) * 64 + lane * 8;
      gstep[t] = 64;
    }
  }

  f16v o0 = {}, o1 = {};   // O cols dh 0..31 / dh 32..63 (col 16 of o1 = lsum)

  for (int kt = 0; kt < Sn; kt += 64) {
    __syncthreads();
#pragma unroll
    for (int t = 0; t < 3; ++t) {
      gload_lds16(gsrc[t], ldst[t]);
      gsrc[t] += gstep[t];
    }
    __syncthreads();

#pragma unroll
    for (int mg = 0; mg < 2; ++mg) {        // key group: 32 keys
      const int row = 32 * mg + l31;        // key for A-frag
      const int s1 = (l31 >> 1) & 3, s2 = (l31 >> 2) & 1;
      s8v a0 = *(const s8v*)&Ka[row][((0 | h) ^ s1) * 8];
      s8v a1 = *(const s8v*)&Ka[row][((2 | h) ^ s1) * 8];
      s8v a2 = *(const s8v*)&Kb[row][((h) ^ s2) * 8];
      f16v sc = {};
      sc = MFMA32(a0, qf[0], sc);
      sc = MFMA32(a1, qf[1], sc);
      sc = MFMA32(a2, qf[2], sc);           // S^T: col=q(lane&31), row=key(reg,h)
      float p[16];
#pragma unroll
      for (int r = 0; r < 16; ++r) p[r] = fexp2(sc[r]);

#pragma unroll
      for (int c2 = 0; c2 < 2; ++c2) {      // 16-key chunks of this group
        const int rb = 8 * c2;
        // pack pairs with baseline's round-half-up (bit-exact), then
        // permlane32_swap exchanges w0.hi <-> w2.lo and w1.hi <-> w3.lo:
        // w0 = {lo0.lo, hi0.lo} = af.x, w2 = {lo0.hi, hi0.hi} = af.z
        // (identical to the old shfl_xor + cndmask network, in 2 VALU ops).
        uint32_t w0 = packbf(p[rb + 0], p[rb + 1]);
        uint32_t w1 = packbf(p[rb + 2], p[rb + 3]);
        uint32_t w2 = packbf(p[rb + 4], p[rb + 5]);
        uint32_t w3 = packbf(p[rb + 6], p[rb + 7]);
        pl32swap(w0, w2);
        pl32swap(w1, w3);
        uint4 af = { w0, w1, w2, w3 };
        const s8v pa = __builtin_bit_cast(s8v, af);
        const int kcv = 2 * mg + c2;        // 16-key chunk index in the 64-key tile
        const int vc = ((2 * kcv + h) ^ (l31 & 7)) * 8;
        const s8v v0 = *(const s8v*)&Vs[l31][vc];
        const s8v v1 = *(const s8v*)&Vs[32 + l31][vc];
        o0 = MFMA32(pa, v0, o0);
        o1 = MFMA32(pa, v1, o1);
      }
    }
  }

  const int b = bh >> 4, hh = bh & 15;
#pragma unroll
  for (int r = 0; r < 16; ++r) {
    const int q = (r & 3) + 8 * (r >> 2) + 4 * h;
    const float lsum = __shfl(o1[r], 16 + (lane & 32), 64);  // col 16 = dh48 = ones row
    const float inv = 1.0f / lsum;
    const int s = q0 + wave * 32 + q;
    const size_t base = ((size_t)(b * Sn + s)) * Dn + hh * DhN;
    og[base + l31] = f2b(o0[r] * inv);
    if (l31 < 16) og[base + 32 + l31] = f2b(o1[r] * inv);
  }
}

extern "C" void kernel_launch(void* const* d_in, const int* in_sizes, int n_in,
                              void* d_out, int out_size, void* d_ws, size_t ws_size,
                              hipStream_t stream) {
  (void)in_sizes; (void)n_in; (void)out_size; (void)ws_size;
  const float* x  = (const float*)d_in[0];
  const float* Wq = (const float*)d_in[1];
  const float* bq = (const float*)d_in[2];
  const float* Wk = (const float*)d_in[3];
  const float* bk = (const float*)d_in[4];
  const float* Wv = (const float*)d_in[5];
  const float* bv = (const float*)d_in[6];
  const float* Wo = (const float*)d_in[7];
  const float* bo = (const float*)d_in[8];

  size_t off = 0;
  auto alloc = [&](size_t bytes) {
    void* p = (char*)d_ws + off;
    off += (bytes + 255) & ~(size_t)255;
    return p;
  };
  ushort* xb    = (ushort*)alloc((size_t)MS * Dn * 2);
  ushort* Wqkvb = (ushort*)alloc((size_t)3 * Dn * Dn * 2);
  ushort* Wob   = (ushort*)alloc((size_t)Dn * Dn * 2);
  ushort* qbuf  = (ushort*)alloc((size_t)Bn * Hn * Sn * Dp * 2);
  ushort* kbuf  = (ushort*)alloc((size_t)Bn * Hn * Sn * Dp * 2);
  ushort* vbuf  = (ushort*)alloc((size_t)Bn * Hn * DhN * Sn * 2);
  ushort* ao    = (ushort*)alloc((size_t)MS * Dn * 2);

  cvt_all<<<6144 + 4 * 576, 256, 0, stream>>>(x, Wq, Wk, Wv, Wo, xb, Wqkvb, Wob);

  const dim3 blk(256);
  // scale = log2(e)/sqrt(48): softmax computed in exp2 domain
  const float qscale = 0.20823510929813633f;
  gemm_qkv<<<dim3(18, MS / 128), blk, 0, stream>>>(xb, Wqkvb, bq, bk, bv,
                                                   qbuf, kbuf, vbuf, qscale);

  attn_kernel<<<dim3(Sn / 128, Bn * Hn), blk, 0, stream>>>(qbuf, kbuf, vbuf, ao);

  gemm_out<<<dim3(6, MS / 128), blk, 0, stream>>>(ao, Wob, bo, (float*)d_out);
}

// Round 4
// 243.632 us; speedup vs baseline: 1.0434x; 1.0050x over previous
//
#include <hip/hip_runtime.h>
#include <cstdint>
#include <cstddef>

// MultiHeadAttention: B=4, S=2048, D=768, H=16, Dh=48, fp32 I/O.
// bf16 MFMA: cvt_all -> fused QKV GEMM -> flash-attn v11 (32x32 MFMA) -> out GEMM
// v11: 128-key tiles (was 64). Kernel was shown (r3) to be neither HBM- nor
// VALU-bound: FETCH -5.5x and VALU -12% bought 0 us; ~28% of each iteration is
// fixed cost (2 barriers + vmcnt drain + loop overhead) paid 32x. Halve the
// count: stage 24KB/iter (Ka[128][32], Kb[128][16], Vs[64][128]), 16 iters.
// LDS 28KB (4 blocks/CU unchanged - grid-limited). Swizzle algebra carries
// over: XOR keys ((r>>1)&3, (r>>2)&1, r&7) are mg-offset-invariant.
// Carried: packbf (bit-exact), permlane32_swap P-exchange, XCD head swizzle,
// QK skips dh 48..63 pad, frag reads xor-swizzled (b128 floor).

typedef short s8v __attribute__((ext_vector_type(8)));    // 8 x bf16 (4 VGPRs)
typedef float f4v __attribute__((ext_vector_type(4)));    // 16x16 accumulator
typedef float f16v __attribute__((ext_vector_type(16)));  // 32x32 accumulator

static constexpr int Bn = 4, Sn = 2048, Dn = 768, Hn = 16, DhN = 48, Dp = 64;
static constexpr int MS = Bn * Sn;  // 8192 rows

#define MFMA16(a, b, c) __builtin_amdgcn_mfma_f32_16x16x32_bf16((a), (b), (c), 0, 0, 0)
#define MFMA32(a, b, c) __builtin_amdgcn_mfma_f32_32x32x16_bf16((a), (b), (c), 0, 0, 0)

__device__ __forceinline__ int swz4(int r) { return (r + (r >> 2)) & 3; }

__device__ __forceinline__ ushort f2b(float f) {
  return (ushort)((__builtin_bit_cast(uint32_t, f) + 0x8000u) >> 16);
}
// pack hi16(a+0x8000), hi16(b+0x8000) via v_perm_b32 (a -> low half)
__device__ __forceinline__ uint32_t packbf(float a, float b) {
  uint32_t ua = __builtin_bit_cast(uint32_t, a) + 0x8000u;
  uint32_t ub = __builtin_bit_cast(uint32_t, b) + 0x8000u;
  return __builtin_amdgcn_perm(ub, ua, 0x07060302u);
}
// swap upper 32 lanes of a with lower 32 lanes of b (in place, both usable)
__device__ __forceinline__ void pl32swap(uint32_t& a, uint32_t& b) {
  asm("v_permlane32_swap_b32 %0, %1" : "+v"(a), "+v"(b));
}
__device__ __forceinline__ float fexp2(float x) {
  return __builtin_amdgcn_exp2f(x);
}
__device__ __forceinline__ void gload_lds16(const ushort* g, ushort* l) {
  __builtin_amdgcn_global_load_lds(
      (const __attribute__((address_space(1))) uint32_t*)g,
      (__attribute__((address_space(3))) uint32_t*)l, 16, 0, 0);
}

// One launch converts x (6144 blocks) + 4 weights (4*576 blocks) to bf16.
__global__ void cvt_all(const float* __restrict__ x,
                        const float* __restrict__ wq, const float* __restrict__ wk,
                        const float* __restrict__ wv, const float* __restrict__ wo,
                        ushort* __restrict__ xb, ushort* __restrict__ wqkv,
                        ushort* __restrict__ wob) {
  const int bid = blockIdx.x;
  const float* src;
  ushort* dst;
  int i;
  if (bid < 6144) {
    src = x; dst = xb; i = bid * 256 + threadIdx.x;
  } else {
    const int r = (bid - 6144) / 576;
    i = ((bid - 6144) % 576) * 256 + threadIdx.x;
    src = (r == 0) ? wq : (r == 1) ? wk : (r == 2) ? wv : wo;
    dst = (r < 3) ? (wqkv + (size_t)r * Dn * Dn) : wob;
  }
  float4 f = ((const float4*)src)[i];
  ushort4 o = { f2b(f.x), f2b(f.y), f2b(f.z), f2b(f.w) };
  ((ushort4*)dst)[i] = o;
}

// ---- Fused QKV GEMM (A=W, B=x so acc regs = 4 consecutive n). Swizzled LDS.
// region 0 -> q [B,H,S,64] (*qscale), 1 -> k [B,H,S,64], 2 -> v [B,H,48,S]
// (q/k Dh-pad cols 48..63 are never read by attn -> no pad zeroing needed)
__global__ __launch_bounds__(256) void gemm_qkv(
    const ushort* __restrict__ A, const ushort* __restrict__ W,
    const float* __restrict__ bq, const float* __restrict__ bk, const float* __restrict__ bv,
    ushort* __restrict__ outq, ushort* __restrict__ outk, ushort* __restrict__ outv,
    float qscale) {
  __shared__ __align__(16) ushort As[128][32];   // x rows
  __shared__ __align__(16) ushort Bs[128][32];   // W rows
  const int tid = threadIdx.x, lane = tid & 63, wave = tid >> 6;
  const int l15 = lane & 15, g = lane >> 4;
  const int m0 = blockIdx.y * 128, n0 = blockIdx.x * 128;
  const int wqm = (wave >> 1) * 64;   // weight-dim quadrant
  const int wqx = (wave & 1) * 64;    // x-dim quadrant
  f4v acc[4][4] = {};                 // [i=wtile][j=xtile]

  const int slot0 = wave * 128 + lane;
  const int slot1 = slot0 + 64;
  const int r0 = slot0 >> 2, u0 = ((slot0 & 3) ^ swz4(r0 & 15)) * 8;
  const int r1 = slot1 >> 2, u1 = ((slot1 & 3) ^ swz4(r1 & 15)) * 8;
  const ushort* ag0 = A + (size_t)(m0 + r0) * Dn + u0;
  const ushort* ag1 = A + (size_t)(m0 + r1) * Dn + u1;
  const ushort* bg0 = W + (size_t)(n0 + r0) * Dn + u0;
  const ushort* bg1 = W + (size_t)(n0 + r1) * Dn + u1;
  ushort* lA0 = &As[0][0] + slot0 * 8;
  ushort* lA1 = &As[0][0] + slot1 * 8;
  ushort* lB0 = &Bs[0][0] + slot0 * 8;
  ushort* lB1 = &Bs[0][0] + slot1 * 8;
  const int fcol = (g ^ swz4(l15)) * 8;

  for (int k0 = 0; k0 < Dn; k0 += 32) {
    __syncthreads();
    gload_lds16(ag0 + k0, lA0);
    gload_lds16(ag1 + k0, lA1);
    gload_lds16(bg0 + k0, lB0);
    gload_lds16(bg1 + k0, lB1);
    __syncthreads();
    s8v wf[4], xf[4];
#pragma unroll
    for (int i = 0; i < 4; ++i) wf[i] = *(const s8v*)&Bs[wqm + i * 16 + l15][fcol];
#pragma unroll
    for (int j = 0; j < 4; ++j) xf[j] = *(const s8v*)&As[wqx + j * 16 + l15][fcol];
#pragma unroll
    for (int i = 0; i < 4; ++i)
#pragma unroll
      for (int j = 0; j < 4; ++j) acc[i][j] = MFMA16(wf[i], xf[j], acc[i][j]);
  }

  const int region = blockIdx.x / 6;        // uniform per block
  const int nbase = n0 - region * 768;
  const float* bias = (region == 0) ? bq : (region == 1) ? bk : bv;
#pragma unroll
  for (int i = 0; i < 4; ++i) {
    const int n = nbase + wqm + i * 16 + g * 4;   // 4 consecutive n, same head
    const float4 b4 = *(const float4*)&bias[n];
    const int h = n / DhN, dh = n - h * DhN;
#pragma unroll
    for (int j = 0; j < 4; ++j) {
      const int s = m0 + wqx + j * 16 + l15;
      const int b = s >> 11, srow = s & 2047;
      const int bh = b * Hn + h;
      float v0 = acc[i][j][0] + b4.x, v1 = acc[i][j][1] + b4.y;
      float v2 = acc[i][j][2] + b4.z, v3 = acc[i][j][3] + b4.w;
      if (region == 0) { v0 *= qscale; v1 *= qscale; v2 *= qscale; v3 *= qscale; }
      if (region < 2) {
        ushort4 o = { f2b(v0), f2b(v1), f2b(v2), f2b(v3) };
        ushort* dst = region ? outk : outq;
        *(ushort4*)&dst[((size_t)bh * Sn + srow) * Dp + dh] = o;
      } else {
        outv[((size_t)bh * DhN + dh + 0) * Sn + srow] = f2b(v0);
        outv[((size_t)bh * DhN + dh + 1) * Sn + srow] = f2b(v1);
        outv[((size_t)bh * DhN + dh + 2) * Sn + srow] = f2b(v2);
        outv[((size_t)bh * DhN + dh + 3) * Sn + srow] = f2b(v3);
      }
    }
  }
}

// ---- Out projection GEMM (swapped operands, float4 stores). Swizzled LDS.
__global__ __launch_bounds__(256) void gemm_out(
    const ushort* __restrict__ A, const ushort* __restrict__ W,
    const float* __restrict__ bias, float* __restrict__ out) {
  __shared__ __align__(16) ushort As[128][32];
  __shared__ __align__(16) ushort Bs[128][32];
  const int tid = threadIdx.x, lane = tid & 63, wave = tid >> 6;
  const int l15 = lane & 15, g = lane >> 4;
  const int m0 = blockIdx.y * 128, n0 = blockIdx.x * 128;
  const int wqm = (wave >> 1) * 64;
  const int wqx = (wave & 1) * 64;
  f4v acc[4][4] = {};

  const int slot0 = wave * 128 + lane;
  const int slot1 = slot0 + 64;
  const int r0 = slot0 >> 2, u0 = ((slot0 & 3) ^ swz4(r0 & 15)) * 8;
  const int r1 = slot1 >> 2, u1 = ((slot1 & 3) ^ swz4(r1 & 15)) * 8;
  const ushort* ag0 = A + (size_t)(m0 + r0) * Dn + u0;
  const ushort* ag1 = A + (size_t)(m0 + r1) * Dn + u1;
  const ushort* bg0 = W + (size_t)(n0 + r0) * Dn + u0;
  const ushort* bg1 = W + (size_t)(n0 + r1) * Dn + u1;
  ushort* lA0 = &As[0][0] + slot0 * 8;
  ushort* lA1 = &As[0][0] + slot1 * 8;
  ushort* lB0 = &Bs[0][0] + slot0 * 8;
  ushort* lB1 = &Bs[0][0] + slot1 * 8;
  const int fcol = (g ^ swz4(l15)) * 8;

  for (int k0 = 0; k0 < Dn; k0 += 32) {
    __syncthreads();
    gload_lds16(ag0 + k0, lA0);
    gload_lds16(ag1 + k0, lA1);
    gload_lds16(bg0 + k0, lB0);
    gload_lds16(bg1 + k0, lB1);
    __syncthreads();
    s8v wf[4], xf[4];
#pragma unroll
    for (int i = 0; i < 4; ++i) wf[i] = *(const s8v*)&Bs[wqm + i * 16 + l15][fcol];
#pragma unroll
    for (int j = 0; j < 4; ++j) xf[j] = *(const s8v*)&As[wqx + j * 16 + l15][fcol];
#pragma unroll
    for (int i = 0; i < 4; ++i)
#pragma unroll
      for (int j = 0; j < 4; ++j) acc[i][j] = MFMA16(wf[i], xf[j], acc[i][j]);
  }

#pragma unroll
  for (int i = 0; i < 4; ++i) {
    const int n = n0 + wqm + i * 16 + g * 4;
    const float4 b4 = *(const float4*)&bias[n];
#pragma unroll
    for (int j = 0; j < 4; ++j) {
      const int s = m0 + wqx + j * 16 + l15;
      float4 o4 = { acc[i][j][0] + b4.x, acc[i][j][1] + b4.y,
                    acc[i][j][2] + b4.z, acc[i][j][3] + b4.w };
      *(float4*)&out[(size_t)s * Dn + n] = o4;
    }
  }
}

// ---- Flash attention v11. grid = (16, B*H) remapped so XCD c owns heads
// [8c, 8c+8). block 256 (4 waves x 32 q). 32x32x16 MFMA.
// 128-KEY TILES: 16 iters x {stage 24KB via 24 chunks (6/wave), 4 mg groups}.
// Per mg: QK = 3 MFMA (dh 0..47), P = packbf x4 + permlane32_swap x2 per
// 16-key chunk, PV = 2x2 MFMA (ones-row 48 -> lsum).
// LDS 28KB: Ka[128][32] dh0..31, Kb[128][16] dh32..47, Vs[64][128]
// (dh-major; rows 48..63 static: row 48 = 1.0).
__global__ __launch_bounds__(256) void attn_kernel(
    const ushort* __restrict__ qg, const ushort* __restrict__ kg,
    const ushort* __restrict__ vg, ushort* __restrict__ og) {
  __shared__ __align__(16) ushort Ka[128][32];
  __shared__ __align__(16) ushort Kb[128][16];
  __shared__ __align__(16) ushort Vs[64][128];
  const int tid = threadIdx.x;
  const int lane = tid & 63;
  const int wave = tid >> 6;          // 0..3
  const int l31 = lane & 31;
  const int h = lane >> 5;            // 0..1
  // XCD swizzle: lin%8 = XCD c; give XCD c heads [8c,8c+8) x all 16 q-tiles
  // (8 heads x 448KB K/V = 3.6MB fits one 4MB XCD L2). Bijective on [0,1024).
  const int lin = blockIdx.x + (blockIdx.y << 4);
  const int k8 = lin >> 3;
  const int bh = (lin & 7) * 8 + (k8 >> 4);
  const int q0 = (k8 & 15) * 128;
  const ushort* qb = qg + (size_t)bh * Sn * Dp;
  const ushort* kb = kg + (size_t)bh * Sn * Dp;
  const ushort* vb = vg + (size_t)bh * DhN * Sn;

  // static V rows 48..63: row 48 = 1.0 (lsum via MFMA), rest 0.
  // 16 rows x 128 ushorts = 1024 dwords.
#pragma unroll
  for (int t = 0; t < 4; ++t) {
    const int idx = tid + t * 256;            // 0..1023 dwords
    const int row = 48 + (idx >> 6);
    ((uint32_t*)&Vs[row][0])[idx & 63] = (row == 48) ? 0x3F803F80u : 0u;
  }

  // Q B-frags (n=q=lane&31, k=dh): kc 0..2 covers dh 0..47 (pad skipped)
  s8v qf[3];
#pragma unroll
  for (int kc = 0; kc < 3; ++kc)
    qf[kc] = *(const s8v*)(qb + (size_t)(q0 + wave * 32 + l31) * Dp + kc * 16 + h * 8);

  // DMA: 24 x 1KB chunks, wave w takes c = w + 4t (t=0..5) -> exactly 6 each.
  // c 0..7: Ka (16 rows x 4 granules); c 8..11: Kb (32 rows x 2 granules);
  // c 12..23: V (4 rows x 16 granules). Source granule xor-swizzled so frag
  // reads hit uniform 8 lanes/bank-quad.
  const ushort* gsrc[6];
  ushort* ldst[6];
  int gstep[6];
#pragma unroll
  for (int t = 0; t < 6; ++t) {
    const int c = wave + 4 * t;
    if (c < 8) {            // Ka: rows 16c..16c+15, dh 0..31
      const int row = 16 * c + (lane >> 2), j = lane & 3;
      gsrc[t] = kb + (size_t)row * Dp + (j ^ ((row >> 1) & 3)) * 8;
      ldst[t] = &Ka[0][0] + 16 * c * 32 + lane * 8;
      gstep[t] = 128 * Dp;
    } else if (c < 12) {    // Kb: rows 32(c-8)..+31, dh 32..47
      const int row = 32 * (c - 8) + (lane >> 1), j = lane & 1;
      gsrc[t] = kb + (size_t)row * Dp + 32 + (j ^ ((row >> 2) & 1)) * 8;
      ldst[t] = &Kb[0][0] + 32 * (c - 8) * 16 + lane * 8;
      gstep[t] = 128 * Dp;
    } else {                // V: dh rows 4(c-12)..+3, 128 keys (16 granules)
      const int row = 4 * (c - 12) + (lane >> 4), j = lane & 15;
      gsrc[t] = vb + (size_t)row * Sn + (j ^ (row & 7)) * 8;
      ldst[t] = &Vs[0][0] + 4 * (c - 12) * 128 + lane * 8;
      gstep[t] = 128;
    }
  }

  f16v o0 = {}, o1 = {};   // O cols dh 0..31 / dh 32..63 (col 16 of o1 = lsum)

  for (int kt = 0; kt < Sn; kt += 128) {
    __syncthreads();
#pragma unroll
    for (int t = 0; t < 6; ++t) {
      gload_lds16(gsrc[t], ldst[t]);
      gsrc[t] += gstep[t];
    }
    __syncthreads();

#pragma unroll
    for (int mg = 0; mg < 4; ++mg) {        // key group: 32 keys
      const int row = 32 * mg + l31;        // key for A-frag (0..127)
      const int s1 = (l31 >> 1) & 3, s2 = (l31 >> 2) & 1;
      s8v a0 = *(const s8v*)&Ka[row][((0 | h) ^ s1) * 8];
      s8v a1 = *(const s8v*)&Ka[row][((2 | h) ^ s1) * 8];
      s8v a2 = *(const s8v*)&Kb[row][((h) ^ s2) * 8];
      f16v sc = {};
      sc = MFMA32(a0, qf[0], sc);
      sc = MFMA32(a1, qf[1], sc);
      sc = MFMA32(a2, qf[2], sc);           // S^T: col=q(lane&31), row=key(reg,h)
      float p[16];
#pragma unroll
      for (int r = 0; r < 16; ++r) p[r] = fexp2(sc[r]);

#pragma unroll
      for (int c2 = 0; c2 < 2; ++c2) {      // 16-key chunks of this group
        const int rb = 8 * c2;
        // pack pairs (bit-exact baseline rounding), then permlane32_swap:
        // w0 = {lo0.lo, hi0.lo} = af.x, w2 = {lo0.hi, hi0.hi} = af.z.
        uint32_t w0 = packbf(p[rb + 0], p[rb + 1]);
        uint32_t w1 = packbf(p[rb + 2], p[rb + 3]);
        uint32_t w2 = packbf(p[rb + 4], p[rb + 5]);
        uint32_t w3 = packbf(p[rb + 6], p[rb + 7]);
        pl32swap(w0, w2);
        pl32swap(w1, w3);
        uint4 af = { w0, w1, w2, w3 };
        const s8v pa = __builtin_bit_cast(s8v, af);
        const int kcv = 2 * mg + c2;        // 16-key chunk index in 128-key tile
        const int vc = ((2 * kcv + h) ^ (l31 & 7)) * 8;
        const s8v v0 = *(const s8v*)&Vs[l31][vc];
        const s8v v1 = *(const s8v*)&Vs[32 + l31][vc];
        o0 = MFMA32(pa, v0, o0);
        o1 = MFMA32(pa, v1, o1);
      }
    }
  }

  const int b = bh >> 4, hh = bh & 15;
#pragma unroll
  for (int r = 0; r < 16; ++r) {
    const int q = (r & 3) + 8 * (r >> 2) + 4 * h;
    const float lsum = __shfl(o1[r], 16 + (lane & 32), 64);  // col 16 = dh48 = ones row
    const float inv = 1.0f / lsum;
    const int s = q0 + wave * 32 + q;
    const size_t base = ((size_t)(b * Sn + s)) * Dn + hh * DhN;
    og[base + l31] = f2b(o0[r] * inv);
    if (l31 < 16) og[base + 32 + l31] = f2b(o1[r] * inv);
  }
}

extern "C" void kernel_launch(void* const* d_in, const int* in_sizes, int n_in,
                              void* d_out, int out_size, void* d_ws, size_t ws_size,
                              hipStream_t stream) {
  (void)in_sizes; (void)n_in; (void)out_size; (void)ws_size;
  const float* x  = (const float*)d_in[0];
  const float* Wq = (const float*)d_in[1];
  const float* bq = (const float*)d_in[2];
  const float* Wk = (const float*)d_in[3];
  const float* bk = (const float*)d_in[4];
  const float* Wv = (const float*)d_in[5];
  const float* bv = (const float*)d_in[6];
  const float* Wo = (const float*)d_in[7];
  const float* bo = (const float*)d_in[8];

  size_t off = 0;
  auto alloc = [&](size_t bytes) {
    void* p = (char*)d_ws + off;
    off += (bytes + 255) & ~(size_t)255;
    return p;
  };
  ushort* xb    = (ushort*)alloc((size_t)MS * Dn * 2);
  ushort* Wqkvb = (ushort*)alloc((size_t)3 * Dn * Dn * 2);
  ushort* Wob   = (ushort*)alloc((size_t)Dn * Dn * 2);
  ushort* qbuf  = (ushort*)alloc((size_t)Bn * Hn * Sn * Dp * 2);
  ushort* kbuf  = (ushort*)alloc((size_t)Bn * Hn * Sn * Dp * 2);
  ushort* vbuf  = (ushort*)alloc((size_t)Bn * Hn * DhN * Sn * 2);
  ushort* ao    = (ushort*)alloc((size_t)MS * Dn * 2);

  cvt_all<<<6144 + 4 * 576, 256, 0, stream>>>(x, Wq, Wk, Wv, Wo, xb, Wqkvb, Wob);

  const dim3 blk(256);
  // scale = log2(e)/sqrt(48): softmax computed in exp2 domain
  const float qscale = 0.20823510929813633f;
  gemm_qkv<<<dim3(18, MS / 128), blk, 0, stream>>>(xb, Wqkvb, bq, bk, bv,
                                                   qbuf, kbuf, vbuf, qscale);

  attn_kernel<<<dim3(Sn / 128, Bn * Hn), blk, 0, stream>>>(qbuf, kbuf, vbuf, ao);

  gemm_out<<<dim3(6, MS / 128), blk, 0, stream>>>(ao, Wob, bo, (float*)d_out);
}